// Round 8
// baseline (259.061 us; speedup 1.0000x reference)
//
#include <hip/hip_runtime.h>
#include <hip/hip_cooperative_groups.h>
#include <cstdint>
#include <cstddef>

namespace cg = cooperative_groups;

#define LDIM 6
#define BDIM 4
#define QDIM 900
#define CDIM 256
#define NDIM (LDIM*QDIM)   /* 5400 */
#define NN   5408          /* padded per-image stride */
#define T128 43            /* ceil(5400/128) */
#define NT128 (T128*(T128+1)/2) /* 946 lower-tri 128x128 tiles */

typedef float floatx4 __attribute__((ext_vector_type(4)));

__device__ __forceinline__ int sig_off(int b, int n) {
    int l = n / QDIM, q = n - l * QDIM;
    return ((l * BDIM + b) * QDIM + q) * CDIM;
}
__device__ __forceinline__ int logit_off(int b, int n) {
    int l = n / QDIM, q = n - l * QDIM;
    return (l * BDIM + b) * QDIM + q;
}

__device__ __forceinline__ int uf_load(const int* p, int i) {
    return __hip_atomic_load(&p[i], __ATOMIC_RELAXED, __HIP_MEMORY_SCOPE_AGENT);
}
__device__ int uf_find(int* p, int x) {
    int r = x;
    int pr = uf_load(p, r);
    while (pr != r) { r = pr; pr = uf_load(p, r); }
    return r;
}
__device__ void uf_union(int* p, int a, int b) {
    int ra = uf_find(p, a), rb = uf_find(p, b);
    while (ra != rb) {
        int hi = ra > rb ? ra : rb;
        int lo = ra ^ rb ^ hi;
        int old = atomicCAS(&p[hi], hi, lo);
        if (old == hi) return;
        ra = uf_find(p, old);
        rb = uf_find(p, lo);
    }
}

__device__ __forceinline__ int pk_fp8x4(float a, float b, float c, float d) {
    int p = __builtin_amdgcn_cvt_pk_fp8_f32(a, b, 0, false);
    p = __builtin_amdgcn_cvt_pk_fp8_f32(c, d, p, true);
    return p;
}

// Compute output slot for node-index n from the seeded-root bitmap and write the row.
// Seeded root: slot = #seeded roots < n (ascending-root order). Else: slot = S + #non-seeded < n.
__device__ __forceinline__ void slot_write(const float* __restrict__ sig, float* __restrict__ out,
                                           const unsigned long long* __restrict__ bm,
                                           unsigned long long key, int b, int n, int lane) {
    int W = n >> 6;
    unsigned long long below = (1ull << (n & 63)) - 1ull;
    unsigned long long w1 = __hip_atomic_load(&bm[lane], __ATOMIC_RELAXED,
                                              __HIP_MEMORY_SCOPE_AGENT);
    unsigned long long w2 = (lane < 21)
        ? __hip_atomic_load(&bm[64 + lane], __ATOMIC_RELAXED, __HIP_MEMORY_SCOPE_AGENT) : 0ULL;
    int t1 = __popcll(w1), t2 = __popcll(w2);
    int p1 = (lane < W) ? t1 : ((lane == W) ? __popcll(w1 & below) : 0);
    int l2 = 64 + lane;
    int p2 = (l2 < W) ? t2 : ((l2 == W) ? __popcll(w2 & below) : 0);
    unsigned long long packed =
        ((unsigned long long)(t1 + t2) << 32) | (unsigned int)(p1 + p2);
    for (int off = 32; off; off >>= 1) packed += __shfl_down(packed, off);
    packed = __shfl(packed, 0);
    int prefix = (int)(packed & 0xffffffffULL);
    int S = (int)(packed >> 32);

    int slot, node = 0;
    float mk, scv;
    if (key != 0ULL) {
        slot = prefix;
        node = (int)(~(unsigned int)key);
        mk = 1.0f;
        scv = __uint_as_float((unsigned int)(key >> 32));
    } else {
        slot = S + (n - prefix);
        mk = 0.0f; scv = 0.0f;
    }
    float* orow = out + ((size_t)(b * NDIM + slot)) * CDIM + lane * 4;
    if (key != 0ULL) {
        *(float4*)orow = *(const float4*)(sig + sig_off(b, node) + lane * 4);
    } else {
        float4 z = {0.f, 0.f, 0.f, 0.f};
        *(float4*)orow = z;
    }
    if (lane == 0) {
        const size_t M0 = (size_t)BDIM * NDIM * CDIM;
        out[M0 + (size_t)b * NDIM + slot] = mk;
        out[M0 + (size_t)BDIM * NDIM + (size_t)b * NDIM + slot] = scv;
    }
}

// ---------------- Cooperative fused kernel ----------------
__global__ __launch_bounds__(256) void k_fused(
    const float* __restrict__ sig, const float* __restrict__ logits,
    float* __restrict__ out, float* __restrict__ scores, int* __restrict__ parent,
    unsigned long long* __restrict__ compKey, int* __restrict__ selIdx,
    int* __restrict__ Mcnt, unsigned long long* __restrict__ argKey,
    int* __restrict__ done, unsigned long long* __restrict__ bitmap,
    char* __restrict__ Xf8)
{
    cg::grid_group grid = cg::this_grid();
    extern __shared__ char Bs[];   // 32 KB, P2 only

    const int tid = threadIdx.x;
    const int lane = tid & 63, wave = tid >> 6;
    const int gidx = blockIdx.x * 256 + tid;
    const int stride = gridDim.x * 256;
    const int nwaves = gridDim.x * 4;
    const int wgid = blockIdx.x * 4 + wave;

    // P0: zero compKey/bitmap; scores, parent, unordered compaction, argmax
    for (int i = gidx; i < BDIM * NN; i += stride) compKey[i] = 0ULL;
    for (int i = gidx; i < BDIM * 128; i += stride) bitmap[i] = 0ULL;
    for (int b = 0; b < BDIM; b++) {
        int n = gidx;     // stride >= NN: single shot, all threads participate
        int f = 0;
        unsigned long long key = 0ULL;
        if (n < NDIM) {
            float x = logits[logit_off(b, n)];
            float sc = 1.0f / (1.0f + expf(-x));
            scores[b * NN + n] = sc;
            parent[b * NN + n] = n;
            f = (sc >= 0.5f) ? 1 : 0;
            key = ((unsigned long long)__float_as_uint(sc) << 32) | (unsigned int)(~n);
        }
        unsigned long long bal = __ballot(f != 0);
        int cnt = __popcll(bal);
        int rank = __popcll(bal & ((1ull << lane) - 1ull));
        int base = 0;
        if (lane == 0 && cnt) base = atomicAdd(&Mcnt[b], cnt);
        base = __shfl(base, 0);
        if (f) selIdx[b * NN + base + rank] = n;
        for (int off = 32; off; off >>= 1) {
            unsigned long long o = __shfl_down(key, off);
            if (o > key) key = o;
        }
        if (lane == 0 && key) atomicMax(&argKey[b], key);
    }
    __syncthreads();
    if (tid == 0) {
        int prev = __hip_atomic_fetch_add(done, 1, __ATOMIC_ACQ_REL,
                                          __HIP_MEMORY_SCOPE_AGENT);
        if (prev == (int)gridDim.x - 1) {
            for (int b = 0; b < BDIM; b++) {
                if (__hip_atomic_load(&Mcnt[b], __ATOMIC_RELAXED,
                                      __HIP_MEMORY_SCOPE_AGENT) == 0) {
                    unsigned long long k = __hip_atomic_load(&argKey[b], __ATOMIC_RELAXED,
                                                             __HIP_MEMORY_SCOPE_AGENT);
                    selIdx[b * NN + 0] = (int)(~(unsigned int)(k & 0xffffffffULL));
                    __hip_atomic_store(&Mcnt[b], 1, __ATOMIC_RELAXED,
                                       __HIP_MEMORY_SCOPE_AGENT);
                }
            }
        }
    }
    grid.sync();

    // P1: normalize + fp32->fp8, compacted + swizzled
    int M4[BDIM];
    for (int b = 0; b < BDIM; b++)
        M4[b] = __hip_atomic_load(&Mcnt[b], __ATOMIC_RELAXED, __HIP_MEMORY_SCOPE_AGENT);
    for (int b = 0; b < BDIM; b++) {
        for (int g = wgid; g < M4[b]; g += nwaves) {
            int node = selIdx[b * NN + g];
            const float4 v = *(const float4*)(sig + sig_off(b, node) + lane * 4);
            float s = v.x * v.x + v.y * v.y + v.z * v.z + v.w * v.w;
            for (int off = 32; off; off >>= 1) s += __shfl_down(s, off);
            s = __shfl(s, 0);
            float ninv = rsqrtf(s + 1e-12f);
            int p = pk_fp8x4(v.x * ninv, v.y * ninv, v.z * ninv, v.w * ninv);
            int slot = (lane >> 2) ^ (g & 15);
            *(int*)(Xf8 + ((size_t)(b * NN + g)) * 256 + slot * 16 + (lane & 3) * 4) = p;
        }
    }
    grid.sync();

    // P2: fp8 MFMA pairwise sims, 128x128 tiles, grid-stride over tiles
    const int rsel = lane & 15, quad = lane >> 4;
    for (int tl = blockIdx.x; tl < NT128 * BDIM; tl += gridDim.x) {
        int b = tl & 3, t = tl >> 2;
        int M = M4[b];
        int ti = (int)((sqrtf(8.0f * (float)t + 1.0f) - 1.0f) * 0.5f);
        while ((ti + 1) * (ti + 2) / 2 <= t) ti++;
        while (ti * (ti + 1) / 2 > t) ti--;
        int tj = t - ti * (ti + 1) / 2;
        if (ti * 128 >= M) continue;

        __syncthreads();   // protect previous iteration's LDS readers
        const char* xb = Xf8 + ((size_t)b * NN) * 256;
#pragma unroll
        for (int k = 0; k < 8; k++) {
            int i = wave * 8 + k;
            int row = min(tj * 128 + 4 * i, NN - 4);
            const char* src = xb + (size_t)row * 256 + lane * 16;
            __builtin_amdgcn_global_load_lds(
                (const __attribute__((address_space(1))) unsigned int*)src,
                (__attribute__((address_space(3))) unsigned int*)(Bs + i * 1024),
                16, 0, 0);
        }
        int rA = ti * 128 + wave * 32;
        int gA0 = min(rA + rsel, M - 1);
        int gA1 = min(rA + 16 + rsel, M - 1);
        const char* pA0 = Xf8 + ((size_t)(b * NN + gA0)) * 256;
        const char* pA1 = Xf8 + ((size_t)(b * NN + gA1)) * 256;
        int swA0 = gA0 & 15, swA1 = gA1 & 15;
        __syncthreads();   // drain global_load_lds

        floatx4 acc[2][8];
#pragma unroll
        for (int s = 0; s < 2; s++)
#pragma unroll
            for (int nj = 0; nj < 8; nj++) acc[s][nj] = (floatx4){0.f, 0.f, 0.f, 0.f};
#pragma unroll
        for (int ks = 0; ks < 8; ks++) {
            int ch = ks * 2 + (quad >> 1);
            int ih = (quad & 1) * 8;
            long a0 = *(const long*)(pA0 + ((ch ^ swA0) << 4) + ih);
            long a1 = *(const long*)(pA1 + ((ch ^ swA1) << 4) + ih);
#pragma unroll
            for (int nj = 0; nj < 8; nj++) {
                int lr = nj * 16 + rsel;
                long bb = *(const long*)(Bs + lr * 256 + (((ch ^ (lr & 15)) << 4) + ih));
                acc[0][nj] = __builtin_amdgcn_mfma_f32_16x16x32_fp8_fp8(a0, bb, acc[0][nj], 0, 0, 0);
                acc[1][nj] = __builtin_amdgcn_mfma_f32_16x16x32_fp8_fp8(a1, bb, acc[1][nj], 0, 0, 0);
            }
        }
#pragma unroll
        for (int s = 0; s < 2; s++) {
            int rowA = rA + s * 16 + quad * 4;
#pragma unroll
            for (int nj = 0; nj < 8; nj++) {
                int gj = tj * 128 + nj * 16 + rsel;
#pragma unroll
                for (int r = 0; r < 4; r++) {
                    int gi = rowA + r;
                    if (gi < M && gj < M && gi > gj && acc[s][nj][r] >= 0.8f) {
                        uf_union(parent + b * NN, selIdx[b * NN + gi], selIdx[b * NN + gj]);
                    }
                }
            }
        }
    }
    grid.sync();

    // P3: component stats — compKey max + seeded-root bitmap
    for (int b = 0; b < BDIM; b++) {
        for (int g = gidx; g < M4[b]; g += stride) {
            int node = selIdx[b * NN + g];
            int root = uf_find(parent + b * NN, node);
            unsigned long long key =
                ((unsigned long long)__float_as_uint(scores[b * NN + node]) << 32) |
                (unsigned int)(~node);
            atomicMax(&compKey[b * NN + root], key);
            atomicOr(&bitmap[b * 128 + (root >> 6)], 1ull << (root & 63));
        }
    }
    grid.sync();

    // P4: per-row slot via popcount prefix; write output
    for (int b = 0; b < BDIM; b++) {
        for (int n = wgid; n < NDIM; n += nwaves) {
            unsigned long long key = __hip_atomic_load(&compKey[b * NN + n], __ATOMIC_RELAXED,
                                                       __HIP_MEMORY_SCOPE_AGENT);
            slot_write(sig, out, bitmap + b * 128, key, b, n, lane);
        }
    }
}

// ---------------- Fallback multi-kernel path ----------------
__global__ void k_init(const float* __restrict__ logits, float* __restrict__ scores,
                       int* __restrict__ parent, unsigned long long* __restrict__ compKey,
                       unsigned long long* __restrict__ bitmap, int* __restrict__ selIdx,
                       int* __restrict__ Mcnt, unsigned long long* __restrict__ argKey,
                       int* __restrict__ done) {
    int b = blockIdx.y;
    int n = blockIdx.x * 256 + threadIdx.x;
    int lane = threadIdx.x & 63;
    if (n < NN) compKey[b * NN + n] = 0ULL;
    if (n < 128) bitmap[b * 128 + n] = 0ULL;
    unsigned long long key = 0ULL;
    int f = 0;
    if (n < NDIM) {
        float x = logits[logit_off(b, n)];
        float sc = 1.0f / (1.0f + expf(-x));
        scores[b * NN + n] = sc;
        parent[b * NN + n] = n;
        f = (sc >= 0.5f) ? 1 : 0;
        key = ((unsigned long long)__float_as_uint(sc) << 32) | (unsigned int)(~n);
    }
    unsigned long long bal = __ballot(f != 0);
    int cnt = __popcll(bal);
    int rank = __popcll(bal & ((1ull << lane) - 1ull));
    int base = 0;
    if (lane == 0 && cnt) base = atomicAdd(&Mcnt[b], cnt);
    base = __shfl(base, 0);
    if (f) selIdx[b * NN + base + rank] = n;
    for (int off = 32; off; off >>= 1) {
        unsigned long long o = __shfl_down(key, off);
        if (o > key) key = o;
    }
    if (lane == 0 && key) atomicMax(&argKey[b], key);
    __syncthreads();
    if (threadIdx.x == 0) {
        int prev = __hip_atomic_fetch_add(&done[b], 1, __ATOMIC_ACQ_REL,
                                          __HIP_MEMORY_SCOPE_AGENT);
        if (prev == (int)gridDim.x - 1) {
            if (__hip_atomic_load(&Mcnt[b], __ATOMIC_RELAXED, __HIP_MEMORY_SCOPE_AGENT) == 0) {
                unsigned long long k = __hip_atomic_load(&argKey[b], __ATOMIC_RELAXED,
                                                         __HIP_MEMORY_SCOPE_AGENT);
                selIdx[b * NN + 0] = (int)(~(unsigned int)(k & 0xffffffffULL));
                __hip_atomic_store(&Mcnt[b], 1, __ATOMIC_RELAXED, __HIP_MEMORY_SCOPE_AGENT);
            }
        }
    }
}

__global__ void k_tobf(const float* __restrict__ sig, const int* __restrict__ selIdx,
                       const int* __restrict__ Mcnt, char* __restrict__ Xf8) {
    int b = blockIdx.y;
    int g = (blockIdx.x * blockDim.x + threadIdx.x) >> 6;
    int lane = threadIdx.x & 63;
    if (g >= Mcnt[b]) return;
    int node = selIdx[b * NN + g];
    const float4 v = *(const float4*)(sig + sig_off(b, node) + lane * 4);
    float s = v.x * v.x + v.y * v.y + v.z * v.z + v.w * v.w;
    for (int off = 32; off; off >>= 1) s += __shfl_down(s, off);
    s = __shfl(s, 0);
    float ninv = rsqrtf(s + 1e-12f);
    int p = pk_fp8x4(v.x * ninv, v.y * ninv, v.z * ninv, v.w * ninv);
    int slot = (lane >> 2) ^ (g & 15);
    *(int*)(Xf8 + ((size_t)(b * NN + g)) * 256 + slot * 16 + (lane & 3) * 4) = p;
}

__global__ __launch_bounds__(256) void k_sim_mfma(const char* __restrict__ Xf8,
                                                  const int* __restrict__ selIdx,
                                                  const int* __restrict__ Mcnt,
                                                  int* __restrict__ parent) {
    int bx = blockIdx.x;
    int b = bx & 3;
    int t = bx >> 2;
    int M = Mcnt[b];
    int ti = (int)((sqrtf(8.0f * (float)t + 1.0f) - 1.0f) * 0.5f);
    while ((ti + 1) * (ti + 2) / 2 <= t) ti++;
    while (ti * (ti + 1) / 2 > t) ti--;
    int tj = t - ti * (ti + 1) / 2;
    if (ti * 128 >= M) return;

    extern __shared__ char Bs[];
    int tid = threadIdx.x;
    int lane = tid & 63, wave = tid >> 6;
    int rsel = lane & 15, quad = lane >> 4;

    const char* xb = Xf8 + ((size_t)b * NN) * 256;
#pragma unroll
    for (int k = 0; k < 8; k++) {
        int i = wave * 8 + k;
        int row = min(tj * 128 + 4 * i, NN - 4);
        const char* src = xb + (size_t)row * 256 + lane * 16;
        __builtin_amdgcn_global_load_lds(
            (const __attribute__((address_space(1))) unsigned int*)src,
            (__attribute__((address_space(3))) unsigned int*)(Bs + i * 1024),
            16, 0, 0);
    }
    int rA = ti * 128 + wave * 32;
    int gA0 = min(rA + rsel, M - 1);
    int gA1 = min(rA + 16 + rsel, M - 1);
    const char* pA0 = Xf8 + ((size_t)(b * NN + gA0)) * 256;
    const char* pA1 = Xf8 + ((size_t)(b * NN + gA1)) * 256;
    int swA0 = gA0 & 15, swA1 = gA1 & 15;
    __syncthreads();

    floatx4 acc[2][8];
#pragma unroll
    for (int s = 0; s < 2; s++)
#pragma unroll
        for (int nj = 0; nj < 8; nj++) acc[s][nj] = (floatx4){0.f, 0.f, 0.f, 0.f};
#pragma unroll
    for (int ks = 0; ks < 8; ks++) {
        int ch = ks * 2 + (quad >> 1);
        int ih = (quad & 1) * 8;
        long a0 = *(const long*)(pA0 + ((ch ^ swA0) << 4) + ih);
        long a1 = *(const long*)(pA1 + ((ch ^ swA1) << 4) + ih);
#pragma unroll
        for (int nj = 0; nj < 8; nj++) {
            int lr = nj * 16 + rsel;
            long bb = *(const long*)(Bs + lr * 256 + (((ch ^ (lr & 15)) << 4) + ih));
            acc[0][nj] = __builtin_amdgcn_mfma_f32_16x16x32_fp8_fp8(a0, bb, acc[0][nj], 0, 0, 0);
            acc[1][nj] = __builtin_amdgcn_mfma_f32_16x16x32_fp8_fp8(a1, bb, acc[1][nj], 0, 0, 0);
        }
    }
#pragma unroll
    for (int s = 0; s < 2; s++) {
        int rowA = rA + s * 16 + quad * 4;
#pragma unroll
        for (int nj = 0; nj < 8; nj++) {
            int gj = tj * 128 + nj * 16 + rsel;
#pragma unroll
            for (int r = 0; r < 4; r++) {
                int gi = rowA + r;
                if (gi < M && gj < M && gi > gj && acc[s][nj][r] >= 0.8f) {
                    uf_union(parent + b * NN, selIdx[b * NN + gi], selIdx[b * NN + gj]);
                }
            }
        }
    }
}

__global__ void k_stats(int* __restrict__ parent, const int* __restrict__ selIdx,
                        const int* __restrict__ Mcnt, const float* __restrict__ scores,
                        unsigned long long* __restrict__ compKey,
                        unsigned long long* __restrict__ bitmap) {
    int b = blockIdx.y;
    int g = blockIdx.x * 256 + threadIdx.x;
    if (g >= Mcnt[b]) return;
    int node = selIdx[b * NN + g];
    int root = uf_find(parent + b * NN, node);
    unsigned long long key =
        ((unsigned long long)__float_as_uint(scores[b * NN + node]) << 32) |
        (unsigned int)(~node);
    atomicMax(&compKey[b * NN + root], key);
    atomicOr(&bitmap[b * 128 + (root >> 6)], 1ull << (root & 63));
}

__global__ void k_write(const float* __restrict__ sig,
                        const unsigned long long* __restrict__ compKey,
                        const unsigned long long* __restrict__ bitmap,
                        float* __restrict__ out) {
    int b = blockIdx.y;
    int wave = threadIdx.x >> 6, lane = threadIdx.x & 63;
    int n = blockIdx.x * 4 + wave;
    unsigned long long key = __hip_atomic_load(&compKey[b * NN + n], __ATOMIC_RELAXED,
                                               __HIP_MEMORY_SCOPE_AGENT);
    slot_write(sig, out, bitmap + b * 128, key, b, n, lane);
}

extern "C" void kernel_launch(void* const* d_in, const int* in_sizes, int n_in,
                              void* d_out, int out_size, void* d_ws, size_t ws_size,
                              hipStream_t stream) {
    (void)in_sizes; (void)n_in; (void)out_size; (void)ws_size;
    const float* sig = (const float*)d_in[0];
    const float* logits = (const float*)d_in[1];
    float* out = (float*)d_out;
    char* ws = (char*)d_ws;

    const size_t arr = (size_t)BDIM * NN * 4;
    int* Mcnt = (int*)(ws + 0);                                     // 16 B
    unsigned long long* argKey = (unsigned long long*)(ws + 64);    // 32 B
    int* done = (int*)(ws + 128);                                   // 16 B
    unsigned long long* bitmap = (unsigned long long*)(ws + 256);   // 4 KB
    unsigned long long* compKey = (unsigned long long*)(ws + 256 + 4096);  // 2*arr
    float* scores = (float*)(ws + 256 + 4096 + 2 * arr);
    int* parent   = (int*)(ws + 256 + 4096 + 3 * arr);
    int* selIdx   = (int*)(ws + 256 + 4096 + 4 * arr);
    char* Xf8     = (char*)(ws + 256 + 4096 + 5 * arr);             // 5.5 MB

    hipMemsetAsync(ws, 0, 256, stream);   // Mcnt / argKey / done

    // Try the cooperative fused kernel with an occupancy-sized grid.
    hipError_t err = hipErrorUnknown;
    int nb = 0;
    if (hipOccupancyMaxActiveBlocksPerMultiprocessor(&nb, k_fused, 256, 32768) == hipSuccess
        && nb > 0) {
        int grid = nb * 256;
        if (grid > 1024) grid = 1024;
        void* args[] = {(void*)&sig, (void*)&logits, (void*)&out, (void*)&scores,
                        (void*)&parent, (void*)&compKey, (void*)&selIdx, (void*)&Mcnt,
                        (void*)&argKey, (void*)&done, (void*)&bitmap, (void*)&Xf8};
        err = hipLaunchCooperativeKernel((const void*)k_fused, dim3(grid), dim3(256),
                                         args, 32768, stream);
    }
    if (err != hipSuccess) {
        // Fallback: proven multi-kernel path (same workspace, same semantics)
        k_init<<<dim3((NN + 255) / 256, BDIM), 256, 0, stream>>>(
            logits, scores, parent, compKey, bitmap, selIdx, Mcnt, argKey, done);
        k_tobf<<<dim3((NDIM + 3) / 4, BDIM), 256, 0, stream>>>(sig, selIdx, Mcnt, Xf8);
        k_sim_mfma<<<NT128 * BDIM, 256, 32768, stream>>>(Xf8, selIdx, Mcnt, parent);
        k_stats<<<dim3((NDIM + 255) / 256, BDIM), 256, 0, stream>>>(
            parent, selIdx, Mcnt, scores, compKey, bitmap);
        k_write<<<dim3(NDIM / 4, BDIM), 256, 0, stream>>>(sig, compKey, bitmap, out);
    }
}

// Round 9
// 111.594 us; speedup vs baseline: 2.3215x; 2.3215x over previous
//
#include <hip/hip_runtime.h>
#include <cstdint>
#include <cstddef>

#define LDIM 6
#define BDIM 4
#define QDIM 900
#define CDIM 256
#define NDIM (LDIM*QDIM)   /* 5400 */
#define NN   5408          /* padded per-image stride */
#define T128 43            /* ceil(5400/128) */
#define NT128 (T128*(T128+1)/2) /* 946 lower-tri 128x128 tiles */

typedef float floatx4 __attribute__((ext_vector_type(4)));

__device__ __forceinline__ int sig_off(int b, int n) {
    int l = n / QDIM, q = n - l * QDIM;
    return ((l * BDIM + b) * QDIM + q) * CDIM;
}
__device__ __forceinline__ int logit_off(int b, int n) {
    int l = n / QDIM, q = n - l * QDIM;
    return (l * BDIM + b) * QDIM + q;
}

__device__ __forceinline__ int uf_load(const int* p, int i) {
    return __hip_atomic_load(&p[i], __ATOMIC_RELAXED, __HIP_MEMORY_SCOPE_AGENT);
}
__device__ int uf_find(int* p, int x) {
    int r = x;
    int pr = uf_load(p, r);
    while (pr != r) { r = pr; pr = uf_load(p, r); }
    return r;
}
__device__ void uf_union(int* p, int a, int b) {
    int ra = uf_find(p, a), rb = uf_find(p, b);
    while (ra != rb) {
        int hi = ra > rb ? ra : rb;
        int lo = ra ^ rb ^ hi;
        int old = atomicCAS(&p[hi], hi, lo);
        if (old == hi) return;
        ra = uf_find(p, old);
        rb = uf_find(p, lo);
    }
}

__device__ __forceinline__ int pk_fp8x4(float a, float b, float c, float d) {
    int p = __builtin_amdgcn_cvt_pk_fp8_f32(a, b, 0, false);
    p = __builtin_amdgcn_cvt_pk_fp8_f32(c, d, p, true);
    return p;
}

// Output slot for node-index n from the seeded-root bitmap; write the row.
// Seeded root: slot = #seeded roots < n (ascending-root order = reference argsort).
// Else: slot = S + #non-seeded < n. Bijective over [0, NDIM).
__device__ __forceinline__ void slot_write(const float* __restrict__ sig, float* __restrict__ out,
                                           const unsigned long long* __restrict__ bm,
                                           unsigned long long key, int b, int n, int lane) {
    int W = n >> 6;
    unsigned long long below = (1ull << (n & 63)) - 1ull;
    unsigned long long w1 = __hip_atomic_load(&bm[lane], __ATOMIC_RELAXED,
                                              __HIP_MEMORY_SCOPE_AGENT);
    unsigned long long w2 = (lane < 21)
        ? __hip_atomic_load(&bm[64 + lane], __ATOMIC_RELAXED, __HIP_MEMORY_SCOPE_AGENT) : 0ULL;
    int t1 = __popcll(w1), t2 = __popcll(w2);
    int p1 = (lane < W) ? t1 : ((lane == W) ? __popcll(w1 & below) : 0);
    int l2 = 64 + lane;
    int p2 = (l2 < W) ? t2 : ((l2 == W) ? __popcll(w2 & below) : 0);
    unsigned long long packed =
        ((unsigned long long)(t1 + t2) << 32) | (unsigned int)(p1 + p2);
    for (int off = 32; off; off >>= 1) packed += __shfl_down(packed, off);
    packed = __shfl(packed, 0);
    int prefix = (int)(packed & 0xffffffffULL);
    int S = (int)(packed >> 32);

    int slot, node = 0;
    float mk, scv;
    if (key != 0ULL) {
        slot = prefix;
        node = (int)(~(unsigned int)key);
        mk = 1.0f;
        scv = __uint_as_float((unsigned int)(key >> 32));
    } else {
        slot = S + (n - prefix);
        mk = 0.0f; scv = 0.0f;
    }
    float* orow = out + ((size_t)(b * NDIM + slot)) * CDIM + lane * 4;
    if (key != 0ULL) {
        *(float4*)orow = *(const float4*)(sig + sig_off(b, node) + lane * 4);
    } else {
        float4 z = {0.f, 0.f, 0.f, 0.f};
        *(float4*)orow = z;
    }
    if (lane == 0) {
        const size_t M0 = (size_t)BDIM * NDIM * CDIM;
        out[M0 + (size_t)b * NDIM + slot] = mk;
        out[M0 + (size_t)BDIM * NDIM + (size_t)b * NDIM + slot] = scv;
    }
}

// K1: init — zero compKey/bitmap, scores, parent, unordered selIdx compaction,
// per-image argmax key, last-block nothing-selected fallback.
__global__ void k_init(const float* __restrict__ logits, float* __restrict__ scores,
                       int* __restrict__ parent, unsigned long long* __restrict__ compKey,
                       unsigned long long* __restrict__ bitmap, int* __restrict__ selIdx,
                       int* __restrict__ Mcnt, unsigned long long* __restrict__ argKey,
                       int* __restrict__ done) {
    int b = blockIdx.y;
    int n = blockIdx.x * 256 + threadIdx.x;
    int lane = threadIdx.x & 63;
    if (n < NN) compKey[b * NN + n] = 0ULL;
    if (n < 128) bitmap[b * 128 + n] = 0ULL;
    unsigned long long key = 0ULL;
    int f = 0;
    if (n < NDIM) {
        float x = logits[logit_off(b, n)];
        float sc = 1.0f / (1.0f + expf(-x));
        scores[b * NN + n] = sc;
        parent[b * NN + n] = n;
        f = (sc >= 0.5f) ? 1 : 0;
        key = ((unsigned long long)__float_as_uint(sc) << 32) | (unsigned int)(~n);
    }
    unsigned long long bal = __ballot(f != 0);
    int cnt = __popcll(bal);
    int rank = __popcll(bal & ((1ull << lane) - 1ull));
    int base = 0;
    if (lane == 0 && cnt) base = atomicAdd(&Mcnt[b], cnt);
    base = __shfl(base, 0);
    if (f) selIdx[b * NN + base + rank] = n;
    for (int off = 32; off; off >>= 1) {
        unsigned long long o = __shfl_down(key, off);
        if (o > key) key = o;
    }
    if (lane == 0 && key) atomicMax(&argKey[b], key);
    __syncthreads();
    if (threadIdx.x == 0) {
        int prev = __hip_atomic_fetch_add(&done[b], 1, __ATOMIC_ACQ_REL,
                                          __HIP_MEMORY_SCOPE_AGENT);
        if (prev == (int)gridDim.x - 1) {
            if (__hip_atomic_load(&Mcnt[b], __ATOMIC_RELAXED, __HIP_MEMORY_SCOPE_AGENT) == 0) {
                unsigned long long k = __hip_atomic_load(&argKey[b], __ATOMIC_RELAXED,
                                                         __HIP_MEMORY_SCOPE_AGENT);
                selIdx[b * NN + 0] = (int)(~(unsigned int)(k & 0xffffffffULL));
                __hip_atomic_store(&Mcnt[b], 1, __ATOMIC_RELAXED, __HIP_MEMORY_SCOPE_AGENT);
            }
        }
    }
}

// K2: normalize + fp32->fp8(e4m3) compaction, per-row 16B-chunk swizzle (c ^ (g&15)).
__global__ void k_tobf(const float* __restrict__ sig, const int* __restrict__ selIdx,
                       const int* __restrict__ Mcnt, char* __restrict__ Xf8) {
    int b = blockIdx.y;
    int g = (blockIdx.x * blockDim.x + threadIdx.x) >> 6;
    int lane = threadIdx.x & 63;
    if (g >= Mcnt[b]) return;
    int node = selIdx[b * NN + g];
    const float4 v = *(const float4*)(sig + sig_off(b, node) + lane * 4);
    float s = v.x * v.x + v.y * v.y + v.z * v.z + v.w * v.w;
    for (int off = 32; off; off >>= 1) s += __shfl_down(s, off);
    s = __shfl(s, 0);
    float ninv = rsqrtf(s + 1e-12f);
    int p = pk_fp8x4(v.x * ninv, v.y * ninv, v.z * ninv, v.w * ninv);
    int slot = (lane >> 2) ^ (g & 15);
    *(int*)(Xf8 + ((size_t)(b * NN + g)) * 256 + slot * 16 + (lane & 3) * 4) = p;
}

// K3: fp8 MFMA pairwise sims, 128x128 lower-tri tiles; B tile staged to LDS (32 KB).
__global__ __launch_bounds__(256) void k_sim_mfma(const char* __restrict__ Xf8,
                                                  const int* __restrict__ selIdx,
                                                  const int* __restrict__ Mcnt,
                                                  int* __restrict__ parent) {
    int bx = blockIdx.x;
    int b = bx & 3;
    int t = bx >> 2;
    int M = Mcnt[b];
    int ti = (int)((sqrtf(8.0f * (float)t + 1.0f) - 1.0f) * 0.5f);
    while ((ti + 1) * (ti + 2) / 2 <= t) ti++;
    while (ti * (ti + 1) / 2 > t) ti--;
    int tj = t - ti * (ti + 1) / 2;
    if (ti * 128 >= M) return;

    extern __shared__ char Bs[];
    int tid = threadIdx.x;
    int lane = tid & 63, wave = tid >> 6;
    int rsel = lane & 15, quad = lane >> 4;

    const char* xb = Xf8 + ((size_t)b * NN) * 256;
#pragma unroll
    for (int k = 0; k < 8; k++) {
        int i = wave * 8 + k;
        int row = min(tj * 128 + 4 * i, NN - 4);
        const char* src = xb + (size_t)row * 256 + lane * 16;
        __builtin_amdgcn_global_load_lds(
            (const __attribute__((address_space(1))) unsigned int*)src,
            (__attribute__((address_space(3))) unsigned int*)(Bs + i * 1024),
            16, 0, 0);
    }
    int rA = ti * 128 + wave * 32;
    int gA0 = min(rA + rsel, M - 1);
    int gA1 = min(rA + 16 + rsel, M - 1);
    const char* pA0 = Xf8 + ((size_t)(b * NN + gA0)) * 256;
    const char* pA1 = Xf8 + ((size_t)(b * NN + gA1)) * 256;
    int swA0 = gA0 & 15, swA1 = gA1 & 15;
    __syncthreads();

    floatx4 acc[2][8];
#pragma unroll
    for (int s = 0; s < 2; s++)
#pragma unroll
        for (int nj = 0; nj < 8; nj++) acc[s][nj] = (floatx4){0.f, 0.f, 0.f, 0.f};
#pragma unroll
    for (int ks = 0; ks < 8; ks++) {
        int ch = ks * 2 + (quad >> 1);
        int ih = (quad & 1) * 8;
        long a0 = *(const long*)(pA0 + ((ch ^ swA0) << 4) + ih);
        long a1 = *(const long*)(pA1 + ((ch ^ swA1) << 4) + ih);
#pragma unroll
        for (int nj = 0; nj < 8; nj++) {
            int lr = nj * 16 + rsel;
            long bb = *(const long*)(Bs + lr * 256 + (((ch ^ (lr & 15)) << 4) + ih));
            acc[0][nj] = __builtin_amdgcn_mfma_f32_16x16x32_fp8_fp8(a0, bb, acc[0][nj], 0, 0, 0);
            acc[1][nj] = __builtin_amdgcn_mfma_f32_16x16x32_fp8_fp8(a1, bb, acc[1][nj], 0, 0, 0);
        }
    }
#pragma unroll
    for (int s = 0; s < 2; s++) {
        int rowA = rA + s * 16 + quad * 4;
#pragma unroll
        for (int nj = 0; nj < 8; nj++) {
            int gj = tj * 128 + nj * 16 + rsel;
#pragma unroll
            for (int r = 0; r < 4; r++) {
                int gi = rowA + r;
                if (gi < M && gj < M && gi > gj && acc[s][nj][r] >= 0.8f) {
                    uf_union(parent + b * NN, selIdx[b * NN + gi], selIdx[b * NN + gj]);
                }
            }
        }
    }
}

// K4: component stats — packed (score,~idx) max per root + seeded-root bitmap. Wide.
__global__ void k_stats(int* __restrict__ parent, const int* __restrict__ selIdx,
                        const int* __restrict__ Mcnt, const float* __restrict__ scores,
                        unsigned long long* __restrict__ compKey,
                        unsigned long long* __restrict__ bitmap) {
    int b = blockIdx.y;
    int g = blockIdx.x * 256 + threadIdx.x;
    if (g >= Mcnt[b]) return;
    int node = selIdx[b * NN + g];
    int root = uf_find(parent + b * NN, node);
    unsigned long long key =
        ((unsigned long long)__float_as_uint(scores[b * NN + node]) << 32) |
        (unsigned int)(~node);
    atomicMax(&compKey[b * NN + root], key);
    atomicOr(&bitmap[b * 128 + (root >> 6)], 1ull << (root & 63));
}

// K5: parallel slot assignment via bitmap popcount prefix; write all NDIM rows.
__global__ void k_write(const float* __restrict__ sig,
                        const unsigned long long* __restrict__ compKey,
                        const unsigned long long* __restrict__ bitmap,
                        float* __restrict__ out) {
    int b = blockIdx.y;
    int wave = threadIdx.x >> 6, lane = threadIdx.x & 63;
    int n = blockIdx.x * 4 + wave;
    unsigned long long key = __hip_atomic_load(&compKey[b * NN + n], __ATOMIC_RELAXED,
                                               __HIP_MEMORY_SCOPE_AGENT);
    slot_write(sig, out, bitmap + b * 128, key, b, n, lane);
}

extern "C" void kernel_launch(void* const* d_in, const int* in_sizes, int n_in,
                              void* d_out, int out_size, void* d_ws, size_t ws_size,
                              hipStream_t stream) {
    (void)in_sizes; (void)n_in; (void)out_size; (void)ws_size;
    const float* sig = (const float*)d_in[0];
    const float* logits = (const float*)d_in[1];
    float* out = (float*)d_out;
    char* ws = (char*)d_ws;

    const size_t arr = (size_t)BDIM * NN * 4;
    int* Mcnt = (int*)(ws + 0);                                     // 16 B
    unsigned long long* argKey = (unsigned long long*)(ws + 64);    // 32 B
    int* done = (int*)(ws + 128);                                   // 16 B
    unsigned long long* bitmap = (unsigned long long*)(ws + 256);   // 4 KB
    unsigned long long* compKey = (unsigned long long*)(ws + 256 + 4096);  // 2*arr
    float* scores = (float*)(ws + 256 + 4096 + 2 * arr);
    int* parent   = (int*)(ws + 256 + 4096 + 3 * arr);
    int* selIdx   = (int*)(ws + 256 + 4096 + 4 * arr);
    char* Xf8     = (char*)(ws + 256 + 4096 + 5 * arr);             // 5.5 MB

    hipMemsetAsync(ws, 0, 256, stream);   // Mcnt / argKey / done

    k_init<<<dim3((NN + 255) / 256, BDIM), 256, 0, stream>>>(
        logits, scores, parent, compKey, bitmap, selIdx, Mcnt, argKey, done);
    k_tobf<<<dim3((NDIM + 3) / 4, BDIM), 256, 0, stream>>>(sig, selIdx, Mcnt, Xf8);
    k_sim_mfma<<<NT128 * BDIM, 256, 32768, stream>>>(Xf8, selIdx, Mcnt, parent);
    k_stats<<<dim3((NDIM + 255) / 256, BDIM), 256, 0, stream>>>(
        parent, selIdx, Mcnt, scores, compKey, bitmap);
    k_write<<<dim3(NDIM / 4, BDIM), 256, 0, stream>>>(sig, compKey, bitmap, out);
}